// Round 6
// baseline (465.982 us; speedup 1.0000x reference)
//
#include <hip/hip_runtime.h>
#include <hip/hip_bf16.h>
#include <math.h>

// HebbianPlasticLayer: B=DIN=DOUT=4096, fp32 in/out.
// out = y + eta*tanh(y)*s,  y = x@W.T + bias,  s = (x*x/||x||)@sigmoid(alpha).T
// Round 12 (re-resubmit of Round 10 — broker timeouts, never measured):
// R9 measured 247.8us gemm, MfmaUtil 49%, BANK_CONFLICT == #ds_read,
// LDS-BW model at 115% of MFMA -> LDS co-limited. This version:
//   - DELETE the sP path: S-GEMM A-operand fp8(x^2) is computed in-register by
//     squaring the Y-GEMM's bf16 A-fragments (identical (row,k) lane mapping for
//     16x16x32 bf16 and fp8 A-fragments). Removes P8 global buffer, convx p8
//     write, sP staging, sP ds_reads. LDS 144->112 KB, LDS cyc/step 2368->1920.
//   - 3 phases / K-step: Y.s0 | Y.s1 | S.(s0+s1); barriers only after ph1, ph2
//     (ph0->ph1 needs none: both read cur; all WAR >=1 barrier apart). 4->2
//     barriers per K-step.
//   - vmcnt ledger: ph0 +X012, ph1 +X3W01 then vmcnt(6) [drains A8-t],
//     ph2 +A8 then vmcnt(1) [drains bf16-(t+1)]. Never 0 in-loop.

typedef __attribute__((ext_vector_type(4))) float floatx4;
typedef __attribute__((ext_vector_type(8))) short shortx8;
typedef __attribute__((ext_vector_type(4))) int intx4;

#define MAT_N 4096
#define MAT_ELEMS ((size_t)MAT_N * MAT_N)

__device__ __forceinline__ unsigned short f2bf(float f) {
    unsigned int u = __float_as_uint(f);
    unsigned int r = (u + 0x7fffu + ((u >> 16) & 1u)) >> 16;   // RNE
    return (unsigned short)r;
}

__device__ __forceinline__ float bf2f(unsigned short h) {
    return __uint_as_float((unsigned int)h << 16);
}

__device__ __forceinline__ void gload_lds16(const void* gptr, void* lptr) {
    __builtin_amdgcn_global_load_lds(
        (const __attribute__((address_space(1))) unsigned int*)gptr,
        (__attribute__((address_space(3))) unsigned int*)lptr,
        16, 0, 0);
}

__device__ __forceinline__ unsigned lds_off(const void* p) {
    return (unsigned)(unsigned long long)(const __attribute__((address_space(3))) char*)p;
}

template <int OFF>
__device__ __forceinline__ intx4 ldsb128(unsigned addr) {
    intx4 d;
    asm volatile("ds_read_b128 %0, %1 offset:%2" : "=v"(d) : "v"(addr), "i"(OFF));
    return d;
}
template <int OFF>
__device__ __forceinline__ long ldsb64(unsigned addr) {
    long d;
    asm volatile("ds_read_b64 %0, %1 offset:%2" : "=v"(d) : "v"(addr), "i"(OFF));
    return d;
}

// rule #18: MFMA hoists past asm lgkmcnt despite "memory" -> sched_barrier(0)
#define LGKM0() do { asm volatile("s_waitcnt lgkmcnt(0)" ::: "memory"); \
                     __builtin_amdgcn_sched_barrier(0); } while (0)
#define VMCNT(n) asm volatile("s_waitcnt vmcnt(" #n ")" ::: "memory")
#define BARRIER() do { asm volatile("" ::: "memory"); \
                       __builtin_amdgcn_s_barrier(); \
                       asm volatile("" ::: "memory"); } while (0)

// square 8 bf16 -> 8 fp8 e4m3 (byte j = elem j), matches fp8 A-fragment packing
__device__ __forceinline__ long sq8_fp8(shortx8 v) {
    float s0 = bf2f((unsigned short)v[0]); s0 *= s0;
    float s1 = bf2f((unsigned short)v[1]); s1 *= s1;
    float s2 = bf2f((unsigned short)v[2]); s2 *= s2;
    float s3 = bf2f((unsigned short)v[3]); s3 *= s3;
    float s4 = bf2f((unsigned short)v[4]); s4 *= s4;
    float s5 = bf2f((unsigned short)v[5]); s5 *= s5;
    float s6 = bf2f((unsigned short)v[6]); s6 *= s6;
    float s7 = bf2f((unsigned short)v[7]); s7 *= s7;
    int p0 = __builtin_amdgcn_cvt_pk_fp8_f32(s0, s1, 0, false);
    p0 = __builtin_amdgcn_cvt_pk_fp8_f32(s2, s3, p0, true);
    int p1 = __builtin_amdgcn_cvt_pk_fp8_f32(s4, s5, 0, false);
    p1 = __builtin_amdgcn_cvt_pk_fp8_f32(s6, s7, p1, true);
    int2 r = {p0, p1};
    return __builtin_bit_cast(long, r);
}

// ---------- convert x: xb = bf16(x), sumsq[row] += x^2 ----------
__global__ __launch_bounds__(512) void convx_kernel(const float* __restrict__ x,
                                                    unsigned short* __restrict__ xb,
                                                    float* __restrict__ sumsq) {
    size_t base = ((size_t)blockIdx.x * 512 + threadIdx.x) * 8;
    const float4* xp = (const float4*)(x + base);
    float4 a = xp[0], b = xp[1];
    float v[8] = {a.x, a.y, a.z, a.w, b.x, b.y, b.z, b.w};
    shortx8 xo;
    float s = 0.f;
#pragma unroll
    for (int j = 0; j < 8; j++) {
        xo[j] = (short)f2bf(v[j]);
        s += v[j] * v[j];
    }
    *(shortx8*)(xb + base) = xo;
    // wave covers 512 contiguous elems -> single row (4096/row)
    for (int off = 32; off > 0; off >>= 1) s += __shfl_down(s, off, 64);
    if ((threadIdx.x & 63) == 0) atomicAdd(&sumsq[base >> 12], s);
}

// ---------- convert W,alpha: wb = bf16(W), a8 = fp8(sigmoid(alpha)) ----------
__global__ __launch_bounds__(512) void convwa_kernel(const float* __restrict__ W,
                                                     const float* __restrict__ alpha,
                                                     unsigned short* __restrict__ wb,
                                                     unsigned char* __restrict__ a8) {
    size_t base = ((size_t)blockIdx.x * 512 + threadIdx.x) * 8;
    const float4* wp = (const float4*)(W + base);
    const float4* ap = (const float4*)(alpha + base);
    float4 w0 = wp[0], w1 = wp[1], a0 = ap[0], a1 = ap[1];
    float wv[8] = {w0.x, w0.y, w0.z, w0.w, w1.x, w1.y, w1.z, w1.w};
    float av[8] = {a0.x, a0.y, a0.z, a0.w, a1.x, a1.y, a1.z, a1.w};
    shortx8 wo;
    float sg[8];
#pragma unroll
    for (int j = 0; j < 8; j++) {
        wo[j] = (short)f2bf(wv[j]);
        sg[j] = 1.0f / (1.0f + __expf(-av[j]));
    }
    *(shortx8*)(wb + base) = wo;
    int p0 = __builtin_amdgcn_cvt_pk_fp8_f32(sg[0], sg[1], 0, false);
    p0 = __builtin_amdgcn_cvt_pk_fp8_f32(sg[2], sg[3], p0, true);
    int p1 = __builtin_amdgcn_cvt_pk_fp8_f32(sg[4], sg[5], 0, false);
    p1 = __builtin_amdgcn_cvt_pk_fp8_f32(sg[6], sg[7], p1, true);
    int2 pv = {p0, p1};
    *(int2*)(a8 + base) = pv;
}

// ---------- fused dual-GEMM, 3-phase counted-vmcnt schedule ----------
// bf16 LDS rows 128B, 16B-chunk swizzle kc' = kc ^ (row&7) (measured ~1 cyc/read).
// fp8 LDS rows 64B, 8B-slot swizzle slot' = slot ^ (row&6) (2-way = free).
// Both applied via pre-swizzled GLOBAL source; LDS dest stays linear
// (global_load_lds dest is wave-uniform base + lane*16, m104/m173).
__global__ __launch_bounds__(512, 2) void fused_gemm_kernel(
    const unsigned short* __restrict__ X,
    const unsigned short* __restrict__ Wb,
    const unsigned char* __restrict__ A8,
    const float* __restrict__ bias,
    const float* __restrict__ eta_p,
    const float* __restrict__ sumsq,
    float* __restrict__ out) {
    constexpr int K = MAT_N;
    constexpr int N = MAT_N;
    __shared__ __align__(16) unsigned short sX[2][256 * 64];  // 64 KB
    __shared__ __align__(16) unsigned short sW[2][128 * 64];  // 32 KB
    __shared__ __align__(16) unsigned char  sA[2][128 * 64];  // 16 KB

    const int tid = threadIdx.x;
    const int row0 = blockIdx.y * 256;
    const int col0 = blockIdx.x * 128;
    const int lane = tid & 63;
    const int wave = tid >> 6;           // 0..7
    const int wm = (wave >> 1) * 64;     // 4x2 wave grid: 64-row x 64-col each
    const int wn = (wave & 1) * 64;
    const int quad = lane >> 4;
    const int l16 = lane & 15;

    floatx4 accY[4][4], accS[4][4];
#pragma unroll
    for (int i = 0; i < 4; i++)
#pragma unroll
        for (int j = 0; j < 4; j++) {
            accY[i][j] = (floatx4){0.f, 0.f, 0.f, 0.f};
            accS[i][j] = (floatx4){0.f, 0.f, 0.f, 0.f};
        }

    // bf16 staging: per 64-row segment, thread t -> row t>>3, chunk (t&7)^(row&7)
    const int rs  = tid >> 3;
    const int kcg = (tid & 7) ^ (rs & 7);
    const size_t xrow = (size_t)(row0 + rs) * K + (size_t)kcg * 8;
    const size_t wrow = (size_t)(col0 + rs) * K + (size_t)kcg * 8;
    // fp8 staging: per 128-row segment, thread t -> row t>>2, slot (2(t&3))^(row&6)
    const int r8 = tid >> 2;
    const int s8 = (2 * (tid & 3)) ^ (r8 & 6);
    const size_t arow = (size_t)(col0 + r8) * K + (size_t)s8 * 8;

    const unsigned sx0 = lds_off(&sX[0][0]);
    const unsigned sw0 = lds_off(&sW[0][0]);
    const unsigned sa0 = lds_off(&sA[0][0]);

#define PF_X(SEG, BUF, KP) gload_lds16(X + xrow + (size_t)(SEG) * 64 * K + (KP), &sX[BUF][(SEG) * 4096 + tid * 8])
#define PF_W(SEG, BUF, KP) gload_lds16(Wb + wrow + (size_t)(SEG) * 64 * K + (KP), &sW[BUF][(SEG) * 4096 + tid * 8])
#define PF_A8(BUF, KP)     gload_lds16(A8 + arow + (KP), &sA[BUF][tid * 16])

    // prologue: stage K-step 0 into buf 0
    PF_X(0, 0, 0); PF_X(1, 0, 0); PF_X(2, 0, 0); PF_X(3, 0, 0);
    PF_W(0, 0, 0); PF_W(1, 0, 0);
    PF_A8(0, 0);
    VMCNT(0);
    BARRIER();

    long p0f[4], p1f[4];   // fp8(x^2) A-fragments, slices 0/1, built from a[]

    for (int t = 0; t < 64; ++t) {
        const int cur = t & 1;
        const int nx = cur ^ 1;
        const size_t kp = (size_t)((t + 1) & 63) * 64;  // wrap keeps counts uniform
        const unsigned sxc = sx0 + (unsigned)cur * (256 * 64 * 2);
        const unsigned swc = sw0 + (unsigned)cur * (128 * 64 * 2);
        const unsigned sac = sa0 + (unsigned)cur * (128 * 64);

        // ---------------- ph0: Y . slice0 (no trailing barrier) ----------------
        {
            const unsigned kcp = (unsigned)(((0 * 4 + quad) ^ (l16 & 7)) * 16);
            const unsigned ax = sxc + (unsigned)(wm + l16) * 128 + kcp;
            const unsigned bx = swc + (unsigned)(wn + l16) * 128 + kcp;
            intx4 a[4], b[4];
            a[0] = ldsb128<0>(ax); a[1] = ldsb128<2048>(ax);
            a[2] = ldsb128<4096>(ax); a[3] = ldsb128<6144>(ax);
            b[0] = ldsb128<0>(bx); b[1] = ldsb128<2048>(bx);
            b[2] = ldsb128<4096>(bx); b[3] = ldsb128<6144>(bx);
            PF_X(0, nx, kp); PF_X(1, nx, kp); PF_X(2, nx, kp);
            LGKM0();
            __builtin_amdgcn_s_setprio(1);
#pragma unroll
            for (int i = 0; i < 4; ++i)
#pragma unroll
                for (int j = 0; j < 4; ++j)
                    accY[i][j] = __builtin_amdgcn_mfma_f32_16x16x32_bf16(
                        __builtin_bit_cast(shortx8, a[i]),
                        __builtin_bit_cast(shortx8, b[j]), accY[i][j], 0, 0, 0);
            __builtin_amdgcn_s_setprio(0);
#pragma unroll
            for (int i = 0; i < 4; ++i)
                p0f[i] = sq8_fp8(__builtin_bit_cast(shortx8, a[i]));
        }
        // ---------------- ph1: Y . slice1 ----------------
        {
            const unsigned kcp = (unsigned)(((1 * 4 + quad) ^ (l16 & 7)) * 16);
            const unsigned ax = sxc + (unsigned)(wm + l16) * 128 + kcp;
            const unsigned bx = swc + (unsigned)(wn + l16) * 128 + kcp;
            intx4 a[4], b[4];
            a[0] = ldsb128<0>(ax); a[1] = ldsb128<2048>(ax);
            a[2] = ldsb128<4096>(ax); a[3] = ldsb128<6144>(ax);
            b[0] = ldsb128<0>(bx); b[1] = ldsb128<2048>(bx);
            b[2] = ldsb128<4096>(bx); b[3] = ldsb128<6144>(bx);
            PF_X(3, nx, kp); PF_W(0, nx, kp); PF_W(1, nx, kp);
            LGKM0();
            __builtin_amdgcn_s_setprio(1);
#pragma unroll
            for (int i = 0; i < 4; ++i)
#pragma unroll
                for (int j = 0; j < 4; ++j)
                    accY[i][j] = __builtin_amdgcn_mfma_f32_16x16x32_bf16(
                        __builtin_bit_cast(shortx8, a[i]),
                        __builtin_bit_cast(shortx8, b[j]), accY[i][j], 0, 0, 0);
            __builtin_amdgcn_s_setprio(0);
#pragma unroll
            for (int i = 0; i < 4; ++i)
                p1f[i] = sq8_fp8(__builtin_bit_cast(shortx8, a[i]));
            VMCNT(6);   // drains A8-t (oldest); leaves 6 bf16-(t+1) in flight
            BARRIER();
        }
        // ---------------- ph2: S . slice0 + slice1 ----------------
        {
            const unsigned lsp0 = (unsigned)(((0 * 4 + quad) ^ (l16 & 6)) * 8);
            const unsigned lsp1 = (unsigned)(((1 * 4 + quad) ^ (l16 & 6)) * 8);
            const unsigned qxb = sac + (unsigned)(wn + l16) * 64;
            long q0[4], q1[4];
            {
                const unsigned qx0 = qxb + lsp0;
                q0[0] = ldsb64<0>(qx0); q0[1] = ldsb64<1024>(qx0);
                q0[2] = ldsb64<2048>(qx0); q0[3] = ldsb64<3072>(qx0);
            }
            {
                const unsigned qx1 = qxb + lsp1;
                q1[0] = ldsb64<0>(qx1); q1[1] = ldsb64<1024>(qx1);
                q1[2] = ldsb64<2048>(qx1); q1[3] = ldsb64<3072>(qx1);
            }
            PF_A8(nx, kp);
            LGKM0();
            __builtin_amdgcn_s_setprio(1);
#pragma unroll
            for (int i = 0; i < 4; ++i)
#pragma unroll
                for (int j = 0; j < 4; ++j)
                    accS[i][j] = __builtin_amdgcn_mfma_f32_16x16x32_fp8_fp8(
                        p0f[i], q0[j], accS[i][j], 0, 0, 0);
#pragma unroll
            for (int i = 0; i < 4; ++i)
#pragma unroll
                for (int j = 0; j < 4; ++j)
                    accS[i][j] = __builtin_amdgcn_mfma_f32_16x16x32_fp8_fp8(
                        p1f[i], q1[j], accS[i][j], 0, 0, 0);
            __builtin_amdgcn_s_setprio(0);
            VMCNT(1);   // drains 6 bf16-(t+1); leaves A8-(t+1) in flight
            BARRIER();
        }
    }
    VMCNT(0);   // drain the wrapped tail prefetch before epilogue

    const float eta = *eta_p;
#pragma unroll
    for (int i = 0; i < 4; i++) {
#pragma unroll
        for (int r = 0; r < 4; r++) {
            const int grow = row0 + wm + i * 16 + quad * 4 + r;
            const float invn = 1.0f / (sqrtf(sumsq[grow]) + 1e-8f);
#pragma unroll
            for (int j = 0; j < 4; j++) {
                // C/D layout: row = quad*4 + r, col = lane&15  [m89/m91 verified]
                const int gcol = col0 + wn + j * 16 + l16;
                float y = accY[i][j][r] + bias[gcol];
                float s = accS[i][j][r] * invn;
                out[(size_t)grow * N + gcol] = y + eta * tanhf(y) * s;
            }
        }
    }
}

extern "C" void kernel_launch(void* const* d_in, const int* in_sizes, int n_in,
                              void* d_out, int out_size, void* d_ws, size_t ws_size,
                              hipStream_t stream) {
    const float* x     = (const float*)d_in[0];
    const float* W     = (const float*)d_in[1];
    const float* alpha = (const float*)d_in[2];
    const float* eta   = (const float*)d_in[3];
    const float* bias  = (const float*)d_in[4];
    float* out = (float*)d_out;

    // ws: sumsq f32[4096] (16KB pad) | xb 32MB | wb 32MB | a8 16MB
    char* ws = (char*)d_ws;
    float* sumsq = (float*)ws;
    unsigned short* xb = (unsigned short*)(ws + 16384);
    unsigned short* wb = xb + MAT_ELEMS;
    unsigned char*  a8 = (unsigned char*)(wb + MAT_ELEMS);

    hipMemsetAsync(sumsq, 0, MAT_N * sizeof(float), stream);
    convx_kernel<<<MAT_ELEMS / (8 * 512), 512, 0, stream>>>(x, xb, sumsq);
    convwa_kernel<<<MAT_ELEMS / (8 * 512), 512, 0, stream>>>(W, alpha, wb, a8);

    dim3 grid(MAT_N / 128, MAT_N / 256);   // (N-tiles, M-tiles) = (32, 16)
    fused_gemm_kernel<<<grid, 512, 0, stream>>>(xb, wb, a8, bias, eta, sumsq, out);
}

// Round 8
// 418.354 us; speedup vs baseline: 1.1138x; 1.1138x over previous
//
#include <hip/hip_runtime.h>
#include <hip/hip_bf16.h>
#include <math.h>

// HebbianPlasticLayer: B=DIN=DOUT=4096, fp32 in/out.
// out = y + eta*tanh(y)*s,  y = x@W.T + bias,  s = (x*x/||x||)@sigmoid(alpha).T
// Round 14 (resubmit of Round 13 — broker timeout, never measured):
// R12 (in-reg fp8 squaring) REGRESSED 248->291us: +27pts VALUBusy, -8pts
// MfmaUtil -- at 2 waves/SIMD the sq8 VALU chains throttle MFMA issue.
// Revert to R9's measured dataflow (sP staged in LDS, no squaring) and keep
// only the schedule change: 3 phases / 2 barriers per K-step:
//   ph0: Y.s0 (no barrier) | ph1: Y.s1 + vmcnt(6) + barrier | phS: S.(s0+s1)
//   (32 fp8 MFMA) + vmcnt(3) + barrier.
// Ledger (per wave): enter ph0 with 3 fp8-t outstanding; ph0 +X012 (6);
// ph1 +X3W01 (9) -> vmcnt(6) drains fp8-t; phS +P01,A8 (9) -> vmcnt(3)
// drains bf16-(t+1). Never 0 in-loop. WAR: every LDS rewrite >=1 barrier
// after its lgkm-bounded readers (audited incl. removed ph0-barrier).

typedef __attribute__((ext_vector_type(4))) float floatx4;
typedef __attribute__((ext_vector_type(8))) short shortx8;
typedef __attribute__((ext_vector_type(4))) int intx4;

#define MAT_N 4096
#define MAT_ELEMS ((size_t)MAT_N * MAT_N)

__device__ __forceinline__ unsigned short f2bf(float f) {
    unsigned int u = __float_as_uint(f);
    unsigned int r = (u + 0x7fffu + ((u >> 16) & 1u)) >> 16;   // RNE
    return (unsigned short)r;
}

__device__ __forceinline__ void gload_lds16(const void* gptr, void* lptr) {
    __builtin_amdgcn_global_load_lds(
        (const __attribute__((address_space(1))) unsigned int*)gptr,
        (__attribute__((address_space(3))) unsigned int*)lptr,
        16, 0, 0);
}

__device__ __forceinline__ unsigned lds_off(const void* p) {
    return (unsigned)(unsigned long long)(const __attribute__((address_space(3))) char*)p;
}

template <int OFF>
__device__ __forceinline__ intx4 ldsb128(unsigned addr) {
    intx4 d;
    asm volatile("ds_read_b128 %0, %1 offset:%2" : "=v"(d) : "v"(addr), "i"(OFF));
    return d;
}
template <int OFF>
__device__ __forceinline__ long ldsb64(unsigned addr) {
    long d;
    asm volatile("ds_read_b64 %0, %1 offset:%2" : "=v"(d) : "v"(addr), "i"(OFF));
    return d;
}

// rule #18: MFMA hoists past asm lgkmcnt despite "memory" -> sched_barrier(0)
#define LGKM0() do { asm volatile("s_waitcnt lgkmcnt(0)" ::: "memory"); \
                     __builtin_amdgcn_sched_barrier(0); } while (0)
#define VMCNT(n) asm volatile("s_waitcnt vmcnt(" #n ")" ::: "memory")
#define BARRIER() do { asm volatile("" ::: "memory"); \
                       __builtin_amdgcn_s_barrier(); \
                       asm volatile("" ::: "memory"); } while (0)

// ---------- convert x: xb = bf16(x), p8 = fp8(x^2), sumsq[row] += x^2 ----------
__global__ __launch_bounds__(512) void convx_kernel(const float* __restrict__ x,
                                                    unsigned short* __restrict__ xb,
                                                    unsigned char* __restrict__ p8,
                                                    float* __restrict__ sumsq) {
    size_t base = ((size_t)blockIdx.x * 512 + threadIdx.x) * 8;
    const float4* xp = (const float4*)(x + base);
    float4 a = xp[0], b = xp[1];
    float v[8] = {a.x, a.y, a.z, a.w, b.x, b.y, b.z, b.w};
    shortx8 xo;
    float sq[8];
    float s = 0.f;
#pragma unroll
    for (int j = 0; j < 8; j++) {
        xo[j] = (short)f2bf(v[j]);
        sq[j] = v[j] * v[j];
        s += sq[j];
    }
    *(shortx8*)(xb + base) = xo;
    int p0 = __builtin_amdgcn_cvt_pk_fp8_f32(sq[0], sq[1], 0, false);
    p0 = __builtin_amdgcn_cvt_pk_fp8_f32(sq[2], sq[3], p0, true);
    int p1 = __builtin_amdgcn_cvt_pk_fp8_f32(sq[4], sq[5], 0, false);
    p1 = __builtin_amdgcn_cvt_pk_fp8_f32(sq[6], sq[7], p1, true);
    int2 pv = {p0, p1};
    *(int2*)(p8 + base) = pv;
    // wave covers 512 contiguous elems -> single row (4096/row)
    for (int off = 32; off > 0; off >>= 1) s += __shfl_down(s, off, 64);
    if ((threadIdx.x & 63) == 0) atomicAdd(&sumsq[base >> 12], s);
}

// ---------- convert W,alpha: wb = bf16(W), a8 = fp8(sigmoid(alpha)) ----------
__global__ __launch_bounds__(512) void convwa_kernel(const float* __restrict__ W,
                                                     const float* __restrict__ alpha,
                                                     unsigned short* __restrict__ wb,
                                                     unsigned char* __restrict__ a8) {
    size_t base = ((size_t)blockIdx.x * 512 + threadIdx.x) * 8;
    const float4* wp = (const float4*)(W + base);
    const float4* ap = (const float4*)(alpha + base);
    float4 w0 = wp[0], w1 = wp[1], a0 = ap[0], a1 = ap[1];
    float wv[8] = {w0.x, w0.y, w0.z, w0.w, w1.x, w1.y, w1.z, w1.w};
    float av[8] = {a0.x, a0.y, a0.z, a0.w, a1.x, a1.y, a1.z, a1.w};
    shortx8 wo;
    float sg[8];
#pragma unroll
    for (int j = 0; j < 8; j++) {
        wo[j] = (short)f2bf(wv[j]);
        sg[j] = 1.0f / (1.0f + __expf(-av[j]));
    }
    *(shortx8*)(wb + base) = wo;
    int p0 = __builtin_amdgcn_cvt_pk_fp8_f32(sg[0], sg[1], 0, false);
    p0 = __builtin_amdgcn_cvt_pk_fp8_f32(sg[2], sg[3], p0, true);
    int p1 = __builtin_amdgcn_cvt_pk_fp8_f32(sg[4], sg[5], 0, false);
    p1 = __builtin_amdgcn_cvt_pk_fp8_f32(sg[6], sg[7], p1, true);
    int2 pv = {p0, p1};
    *(int2*)(a8 + base) = pv;
}

// ---------- fused dual-GEMM, 3-phase / 2-barrier counted-vmcnt schedule ----------
// bf16 LDS rows 128B, 16B-chunk swizzle kc' = kc ^ (row&7) (2-way = free).
// fp8 LDS rows 64B, 8B-slot swizzle slot' = slot ^ (row&6) (2-way = free).
// Both applied via pre-swizzled GLOBAL source; LDS dest stays linear
// (global_load_lds dest is wave-uniform base + lane*16, m104/m173).
__global__ __launch_bounds__(512, 2) void fused_gemm_kernel(
    const unsigned short* __restrict__ X,
    const unsigned short* __restrict__ Wb,
    const unsigned char* __restrict__ P8,
    const unsigned char* __restrict__ A8,
    const float* __restrict__ bias,
    const float* __restrict__ eta_p,
    const float* __restrict__ sumsq,
    float* __restrict__ out) {
    constexpr int K = MAT_N;
    constexpr int N = MAT_N;
    __shared__ __align__(16) unsigned short sX[2][256 * 64];  // 64 KB
    __shared__ __align__(16) unsigned short sW[2][128 * 64];  // 32 KB
    __shared__ __align__(16) unsigned char  sP[2][256 * 64];  // 32 KB
    __shared__ __align__(16) unsigned char  sA[2][128 * 64];  // 16 KB

    const int tid = threadIdx.x;
    const int row0 = blockIdx.y * 256;
    const int col0 = blockIdx.x * 128;
    const int lane = tid & 63;
    const int wave = tid >> 6;           // 0..7
    const int wm = (wave >> 1) * 64;     // 4x2 wave grid: 64-row x 64-col each
    const int wn = (wave & 1) * 64;
    const int quad = lane >> 4;
    const int l16 = lane & 15;

    floatx4 accY[4][4], accS[4][4];
#pragma unroll
    for (int i = 0; i < 4; i++)
#pragma unroll
        for (int j = 0; j < 4; j++) {
            accY[i][j] = (floatx4){0.f, 0.f, 0.f, 0.f};
            accS[i][j] = (floatx4){0.f, 0.f, 0.f, 0.f};
        }

    // bf16 staging: per 64-row segment, thread t -> row t>>3, chunk (t&7)^(row&7)
    const int rs  = tid >> 3;
    const int kcg = (tid & 7) ^ (rs & 7);
    const size_t xrow = (size_t)(row0 + rs) * K + (size_t)kcg * 8;
    const size_t wrow = (size_t)(col0 + rs) * K + (size_t)kcg * 8;
    // fp8 staging: per 128-row segment, thread t -> row t>>2, slot (2(t&3))^(row&6)
    const int r8 = tid >> 2;
    const int s8 = (2 * (tid & 3)) ^ (r8 & 6);
    const size_t prow = (size_t)(row0 + r8) * K + (size_t)s8 * 8;
    const size_t arow = (size_t)(col0 + r8) * K + (size_t)s8 * 8;

    const unsigned sx0 = lds_off(&sX[0][0]);
    const unsigned sw0 = lds_off(&sW[0][0]);
    const unsigned sp0 = lds_off(&sP[0][0]);
    const unsigned sa0 = lds_off(&sA[0][0]);

#define PF_X(SEG, BUF, KP) gload_lds16(X + xrow + (size_t)(SEG) * 64 * K + (KP), &sX[BUF][(SEG) * 4096 + tid * 8])
#define PF_W(SEG, BUF, KP) gload_lds16(Wb + wrow + (size_t)(SEG) * 64 * K + (KP), &sW[BUF][(SEG) * 4096 + tid * 8])
#define PF_P(SEG, BUF, KP) gload_lds16(P8 + prow + (size_t)(SEG) * 128 * K + (KP), &sP[BUF][(SEG) * 8192 + tid * 16])
#define PF_A8(BUF, KP)     gload_lds16(A8 + arow + (KP), &sA[BUF][tid * 16])

    // prologue: stage K-step 0 into buf 0 (6 bf16, then 3 fp8)
    PF_X(0, 0, 0); PF_X(1, 0, 0); PF_X(2, 0, 0); PF_X(3, 0, 0);
    PF_W(0, 0, 0); PF_W(1, 0, 0);
    PF_P(0, 0, 0); PF_P(1, 0, 0); PF_A8(0, 0);
    VMCNT(3);          // bf16-0 landed; fp8-0 stays in flight (drained @ph1)
    BARRIER();

    for (int t = 0; t < 64; ++t) {
        const int cur = t & 1;
        const int nx = cur ^ 1;
        const size_t kp = (size_t)((t + 1) & 63) * 64;  // wrap keeps counts uniform
        const unsigned sxc = sx0 + (unsigned)cur * (256 * 64 * 2);
        const unsigned swc = sw0 + (unsigned)cur * (128 * 64 * 2);
        const unsigned spc = sp0 + (unsigned)cur * (256 * 64);
        const unsigned sac = sa0 + (unsigned)cur * (128 * 64);

        // ---------------- ph0: Y . slice0 (no trailing barrier) ----------------
        {
            const unsigned kcp = (unsigned)(((0 * 4 + quad) ^ (l16 & 7)) * 16);
            const unsigned ax = sxc + (unsigned)(wm + l16) * 128 + kcp;
            const unsigned bx = swc + (unsigned)(wn + l16) * 128 + kcp;
            intx4 a[4], b[4];
            a[0] = ldsb128<0>(ax); a[1] = ldsb128<2048>(ax);
            a[2] = ldsb128<4096>(ax); a[3] = ldsb128<6144>(ax);
            b[0] = ldsb128<0>(bx); b[1] = ldsb128<2048>(bx);
            b[2] = ldsb128<4096>(bx); b[3] = ldsb128<6144>(bx);
            PF_X(0, nx, kp); PF_X(1, nx, kp); PF_X(2, nx, kp);
            LGKM0();
            __builtin_amdgcn_s_setprio(1);
#pragma unroll
            for (int i = 0; i < 4; ++i)
#pragma unroll
                for (int j = 0; j < 4; ++j)
                    accY[i][j] = __builtin_amdgcn_mfma_f32_16x16x32_bf16(
                        __builtin_bit_cast(shortx8, a[i]),
                        __builtin_bit_cast(shortx8, b[j]), accY[i][j], 0, 0, 0);
            __builtin_amdgcn_s_setprio(0);
        }
        // ---------------- ph1: Y . slice1 ----------------
        {
            const unsigned kcp = (unsigned)(((1 * 4 + quad) ^ (l16 & 7)) * 16);
            const unsigned ax = sxc + (unsigned)(wm + l16) * 128 + kcp;
            const unsigned bx = swc + (unsigned)(wn + l16) * 128 + kcp;
            intx4 a[4], b[4];
            a[0] = ldsb128<0>(ax); a[1] = ldsb128<2048>(ax);
            a[2] = ldsb128<4096>(ax); a[3] = ldsb128<6144>(ax);
            b[0] = ldsb128<0>(bx); b[1] = ldsb128<2048>(bx);
            b[2] = ldsb128<4096>(bx); b[3] = ldsb128<6144>(bx);
            PF_X(3, nx, kp); PF_W(0, nx, kp); PF_W(1, nx, kp);
            LGKM0();
            __builtin_amdgcn_s_setprio(1);
#pragma unroll
            for (int i = 0; i < 4; ++i)
#pragma unroll
                for (int j = 0; j < 4; ++j)
                    accY[i][j] = __builtin_amdgcn_mfma_f32_16x16x32_bf16(
                        __builtin_bit_cast(shortx8, a[i]),
                        __builtin_bit_cast(shortx8, b[j]), accY[i][j], 0, 0, 0);
            __builtin_amdgcn_s_setprio(0);
            VMCNT(6);   // drains fp8-t (oldest 3); leaves bf16-(t+1) in flight
            BARRIER();
        }
        // ---------------- phS: S . slice0 + slice1 (32 fp8 MFMA) ----------------
        {
            const unsigned lsp0 = (unsigned)(((0 * 4 + quad) ^ (l16 & 6)) * 8);
            const unsigned lsp1 = (unsigned)(((1 * 4 + quad) ^ (l16 & 6)) * 8);
            const unsigned pxb = spc + (unsigned)(wm + l16) * 64;
            const unsigned qxb = sac + (unsigned)(wn + l16) * 64;
            long p0[4], q0[4], p1[4], q1[4];
            {
                const unsigned px0 = pxb + lsp0;
                p0[0] = ldsb64<0>(px0); p0[1] = ldsb64<1024>(px0);
                p0[2] = ldsb64<2048>(px0); p0[3] = ldsb64<3072>(px0);
            }
            {
                const unsigned qx0 = qxb + lsp0;
                q0[0] = ldsb64<0>(qx0); q0[1] = ldsb64<1024>(qx0);
                q0[2] = ldsb64<2048>(qx0); q0[3] = ldsb64<3072>(qx0);
            }
            {
                const unsigned px1 = pxb + lsp1;
                p1[0] = ldsb64<0>(px1); p1[1] = ldsb64<1024>(px1);
                p1[2] = ldsb64<2048>(px1); p1[3] = ldsb64<3072>(px1);
            }
            {
                const unsigned qx1 = qxb + lsp1;
                q1[0] = ldsb64<0>(qx1); q1[1] = ldsb64<1024>(qx1);
                q1[2] = ldsb64<2048>(qx1); q1[3] = ldsb64<3072>(qx1);
            }
            PF_P(0, nx, kp); PF_P(1, nx, kp); PF_A8(nx, kp);
            LGKM0();
            __builtin_amdgcn_s_setprio(1);
#pragma unroll
            for (int i = 0; i < 4; ++i)
#pragma unroll
                for (int j = 0; j < 4; ++j)
                    accS[i][j] = __builtin_amdgcn_mfma_f32_16x16x32_fp8_fp8(
                        p0[i], q0[j], accS[i][j], 0, 0, 0);
#pragma unroll
            for (int i = 0; i < 4; ++i)
#pragma unroll
                for (int j = 0; j < 4; ++j)
                    accS[i][j] = __builtin_amdgcn_mfma_f32_16x16x32_fp8_fp8(
                        p1[i], q1[j], accS[i][j], 0, 0, 0);
            __builtin_amdgcn_s_setprio(0);
            VMCNT(3);   // drains bf16-(t+1); leaves fp8-(t+1) in flight
            BARRIER();
        }
    }
    VMCNT(0);   // drain the wrapped tail prefetches before epilogue

    const float eta = *eta_p;
#pragma unroll
    for (int i = 0; i < 4; i++) {
#pragma unroll
        for (int r = 0; r < 4; r++) {
            const int grow = row0 + wm + i * 16 + quad * 4 + r;
            const float invn = 1.0f / (sqrtf(sumsq[grow]) + 1e-8f);
#pragma unroll
            for (int j = 0; j < 4; j++) {
                // C/D layout: row = quad*4 + r, col = lane&15  [m89/m91 verified]
                const int gcol = col0 + wn + j * 16 + l16;
                float y = accY[i][j][r] + bias[gcol];
                float s = accS[i][j][r] * invn;
                out[(size_t)grow * N + gcol] = y + eta * tanhf(y) * s;
            }
        }
    }
}

extern "C" void kernel_launch(void* const* d_in, const int* in_sizes, int n_in,
                              void* d_out, int out_size, void* d_ws, size_t ws_size,
                              hipStream_t stream) {
    const float* x     = (const float*)d_in[0];
    const float* W     = (const float*)d_in[1];
    const float* alpha = (const float*)d_in[2];
    const float* eta   = (const float*)d_in[3];
    const float* bias  = (const float*)d_in[4];
    float* out = (float*)d_out;

    // ws: sumsq f32[4096] (16KB pad) | xb 32MB | wb 32MB | p8 16MB | a8 16MB
    char* ws = (char*)d_ws;
    float* sumsq = (float*)ws;
    unsigned short* xb = (unsigned short*)(ws + 16384);
    unsigned short* wb = xb + MAT_ELEMS;
    unsigned char*  p8 = (unsigned char*)(wb + MAT_ELEMS);
    unsigned char*  a8 = p8 + MAT_ELEMS;

    hipMemsetAsync(sumsq, 0, MAT_N * sizeof(float), stream);
    convx_kernel<<<MAT_ELEMS / (8 * 512), 512, 0, stream>>>(x, xb, p8, sumsq);
    convwa_kernel<<<MAT_ELEMS / (8 * 512), 512, 0, stream>>>(W, alpha, wb, a8);

    dim3 grid(MAT_N / 128, MAT_N / 256);   // (N-tiles, M-tiles) = (32, 16)
    fused_gemm_kernel<<<grid, 512, 0, stream>>>(xb, wb, p8, a8, bias, eta, sumsq, out);
}